// Round 11
// baseline (153.297 us; speedup 1.0000x reference)
//
#include <hip/hip_runtime.h>

#define S_LEN 2048
#define HID 512
#define DIN 256
#define WIN 33
#define MROWS 8192
#define VTB 2080          // per-batch padded width of Vt (16 + 2048 + 16)
#define VTROW 8320        // 4 * VTB
#define SCALE_INV 0.04419417382415922f   // 1/sqrt(512)

typedef __attribute__((ext_vector_type(8))) short short8;
typedef __attribute__((ext_vector_type(4))) float f32x4;

__device__ __forceinline__ unsigned short f2bf(float f) {
    unsigned u = __builtin_bit_cast(unsigned, f);
    u += 0x7fffu + ((u >> 16) & 1u);
    return (unsigned short)(u >> 16);
}
__device__ __forceinline__ float bf2f(unsigned short h) {
    unsigned u = ((unsigned)h) << 16;
    return __builtin_bit_cast(float, u);
}
__device__ __forceinline__ void gl_lds16(const unsigned short* g, unsigned short* l) {
    __builtin_amdgcn_global_load_lds(
        (__attribute__((address_space(1))) unsigned int*)(g),
        (__attribute__((address_space(3))) unsigned int*)(l),
        16, 0, 0);
}

// ---------------- prep: x->bf16 + W0 transpose (BW-bound minimum) ----------------
__global__ __launch_bounds__(256) void prep_kernel(
    const float* __restrict__ x, const float* __restrict__ W0,
    unsigned short* __restrict__ xb, unsigned short* __restrict__ Wt0)
{
    __shared__ float tile[32][33];
    const int blk = blockIdx.x, tid = threadIdx.x;
    if (blk < 2048) {                        // convert x (2M elems, 4/thread)
        int i = (blk * 256 + tid) * 4;
        float4 v = *(const float4*)(x + i);
        unsigned lo = (unsigned)f2bf(v.x) | ((unsigned)f2bf(v.y) << 16);
        unsigned hi = (unsigned)f2bf(v.z) | ((unsigned)f2bf(v.w) << 16);
        uint2 p; p.x = lo; p.y = hi;
        *(uint2*)(xb + i) = p;
    } else {                                 // W0 transpose: 128 tiles of 32x32
        int tt = blk - 2048;
        int kt = tt & 7, nt = tt >> 3;
        int k0 = kt * 32, n0 = nt * 32;
        int tx = tid & 31, ty = tid >> 5;
        for (int j = 0; j < 32; j += 8)
            tile[ty + j][tx] = W0[(size_t)(k0 + ty + j) * HID + n0 + tx];
        __syncthreads();
        for (int j = 0; j < 32; j += 8)
            Wt0[(size_t)(n0 + ty + j) * DIN + k0 + tx] = f2bf(tile[tx][ty + j]);
    }
}

// ---------------- 128x128 MFMA GEMM, 3-buf pipeline, 2 tiles in flight (T3+T4) ----------------
// grid (NB_N, NB_M): blockIdx.x = bn (fastest), blockIdx.y = bm.
// MODE 0: bn<4: C0 = relu(A@Bt^T + bias) bf16. bn in [4,20): transpose one
//         32x32 tile of {Wq,Wk,Wv,W1} into bf16 [N][K]. bn in [20,25):
//         Vt pad zeroing + out init (side work on idle CUs).
// MODE 1: QKV split (bn<4 -> C0=Q, bn<8 -> C1=K, else transposed LDS-bounced
//         write into C2=Vt).
// MODE 2: h2 = relu(A@Bt^T + bias); out += h2 @ Wout (atomicAdd, out pre-init
//         with bout). No h2 materialization.
template<int K, int MODE>
__global__ __launch_bounds__(256) void gemm128_kernel(
    const unsigned short* __restrict__ A,
    const unsigned short* __restrict__ Bt,
    const float* __restrict__ bias,
    unsigned short* __restrict__ C0,
    unsigned short* __restrict__ C1,
    unsigned short* __restrict__ C2,
    const float* __restrict__ Wout,
    float* __restrict__ outp,
    const float* __restrict__ Wqf,
    const float* __restrict__ Wkf,
    const float* __restrict__ Wvf,
    const float* __restrict__ W1f,
    const float* __restrict__ boutf,
    unsigned short* __restrict__ WtqkvO,
    unsigned short* __restrict__ Wt1O,
    unsigned short* __restrict__ VtO,
    float* __restrict__ outpO)
{
    __shared__ __align__(16) unsigned short SMEM[24576];  // 3 bufs x (A 4096 | B 4096)
    const int tid = threadIdx.x;
    const int lane = tid & 63, wid = tid >> 6;
    const int bn = blockIdx.x, bm = blockIdx.y;
    const int wr = wid >> 1, wc = wid & 1;
    const int r16 = lane & 15, kq = lane >> 4;
    const int NT = K / 32;

    if constexpr (MODE == 0) {
        if (bn >= 4) {                        // side work on otherwise-idle CUs
            if (bn < 20) {                    // 1024 transpose tiles (4 x 512x512)
                float (*tile)[33] = (float(*)[33])SMEM;
                int tt = (bn - 4) * 64 + bm;  // 0..1023
                int z = tt >> 8, r = tt & 255, kt = r & 15, nt = r >> 4;
                const float* in; unsigned short* out;
                if (z == 0)      { in = Wqf; out = WtqkvO; }
                else if (z == 1) { in = Wkf; out = WtqkvO + 512 * 512; }
                else if (z == 2) { in = Wvf; out = WtqkvO + 2 * 512 * 512; }
                else             { in = W1f; out = Wt1O; }
                int k0 = kt * 32, n0 = nt * 32;
                int tx = tid & 31, ty = tid >> 5;
                for (int j = 0; j < 32; j += 8)
                    tile[ty + j][tx] = in[(size_t)(k0 + ty + j) * HID + n0 + tx];
                __syncthreads();
                for (int j = 0; j < 32; j += 8)
                    out[(size_t)(n0 + ty + j) * HID + k0 + tx] = f2bf(tile[tx][ty + j]);
            } else {                          // Vt pads (256 blocks) + out init (16)
                int idx = (bn - 20) * 64 + bm;   // 0..319
                if (idx < 256) {
                    int t = idx * 256 + tid;     // 0..65535
                    int v = t >> 7, s = t & 127;
                    int b2 = s >> 5, p = s & 31;
                    int off = (p < 16) ? p : (2048 + p);
                    VtO[(size_t)v * VTROW + b2 * VTB + off] = 0;
                } else if (idx < 272) {
                    int i = ((idx - 256) * 256 + tid) * 4;
                    float4 o; o.x = boutf[0]; o.y = boutf[1]; o.z = boutf[0]; o.w = boutf[1];
                    *(float4*)(outpO + i) = o;
                }
            }
            return;
        }
    }

    f32x4 acc[4][4] = {};

    const int c0 = tid, c1 = tid + 256;   // chunk = kblk*128 + row
    const unsigned short* aS0 = A + (size_t)(bm * 128 + (c0 & 127)) * K + (c0 >> 7) * 8;
    const unsigned short* aS1 = A + (size_t)(bm * 128 + (c1 & 127)) * K + (c1 >> 7) * 8;
    const unsigned short* bS0 = Bt + (size_t)(bn * 128 + (c0 & 127)) * K + (c0 >> 7) * 8;
    const unsigned short* bS1 = Bt + (size_t)(bn * 128 + (c1 & 127)) * K + (c1 >> 7) * 8;

    #define STAGE(buf, kt) do { \
        gl_lds16(aS0 + (kt) * 32, SMEM + (buf) * 8192 + c0 * 8); \
        gl_lds16(aS1 + (kt) * 32, SMEM + (buf) * 8192 + c1 * 8); \
        gl_lds16(bS0 + (kt) * 32, SMEM + (buf) * 8192 + 4096 + c0 * 8); \
        gl_lds16(bS1 + (kt) * 32, SMEM + (buf) * 8192 + 4096 + c1 * 8); \
    } while (0)

    STAGE(0, 0);
    STAGE(1, 1);
    int cur = 0;
    for (int kt = 0; kt < NT; ++kt) {
        if (kt + 2 < NT) {
            STAGE((cur + 2) % 3, kt + 2);
            // 12 outstanding -> drain to 8: tile kt landed, kt+1/kt+2 in flight
            asm volatile("s_waitcnt vmcnt(8)" ::: "memory");
        } else if (kt + 1 < NT) {
            asm volatile("s_waitcnt vmcnt(4)" ::: "memory");
        } else {
            asm volatile("s_waitcnt vmcnt(0)" ::: "memory");
        }
        __builtin_amdgcn_sched_barrier(0);
        __builtin_amdgcn_s_barrier();            // buf[cur] fully written, all waves
        __builtin_amdgcn_sched_barrier(0);

        const unsigned short* ab = SMEM + cur * 8192;
        const unsigned short* bb = ab + 4096;
        short8 af[4], bfr[4];
        #pragma unroll
        for (int mi = 0; mi < 4; ++mi)
            af[mi] = *(const short8*)(ab + kq * 1024 + (wr * 64 + mi * 16 + r16) * 8);
        #pragma unroll
        for (int ni = 0; ni < 4; ++ni)
            bfr[ni] = *(const short8*)(bb + kq * 1024 + (wc * 64 + ni * 16 + r16) * 8);
        #pragma unroll
        for (int mi = 0; mi < 4; ++mi)
            #pragma unroll
            for (int ni = 0; ni < 4; ++ni)
                acc[mi][ni] = __builtin_amdgcn_mfma_f32_16x16x32_bf16(af[mi], bfr[ni], acc[mi][ni], 0, 0, 0);

        asm volatile("s_waitcnt lgkmcnt(0)" ::: "memory");  // my ds_reads of buf[cur] done
        __builtin_amdgcn_sched_barrier(0);
        __builtin_amdgcn_s_barrier();            // everyone done reading buf[cur]
        __builtin_amdgcn_sched_barrier(0);
        cur = (cur + 1) % 3;
    }
    #undef STAGE

    if constexpr (MODE == 0) {
        #pragma unroll
        for (int mi = 0; mi < 4; ++mi) {
            int row0 = bm * 128 + wr * 64 + mi * 16 + kq * 4;
            #pragma unroll
            for (int ni = 0; ni < 4; ++ni) {
                int col = bn * 128 + wc * 64 + ni * 16 + r16;
                float bv = bias[col];
                #pragma unroll
                for (int r = 0; r < 4; ++r) {
                    float v = fmaxf(acc[mi][ni][r] + bv, 0.0f);
                    C0[(size_t)(row0 + r) * HID + col] = f2bf(v);
                }
            }
        }
    } else if constexpr (MODE == 1) {
        if (bn < 8) {
            unsigned short* dst = (bn < 4) ? C0 : C1;
            int cb = (bn & 3) * 128 + wc * 64;
            #pragma unroll
            for (int mi = 0; mi < 4; ++mi) {
                int row0 = bm * 128 + wr * 64 + mi * 16 + kq * 4;
                #pragma unroll
                for (int ni = 0; ni < 4; ++ni) {
                    int col = cb + ni * 16 + r16;
                    #pragma unroll
                    for (int r = 0; r < 4; ++r)
                        dst[(size_t)(row0 + r) * HID + col] = f2bf(acc[mi][ni][r]);
                }
            }
        } else {
            // V tile (rows t, cols v) -> Vt[v][t] via LDS bounce, 2 passes of 64 v-rows
            const int bb  = (bm * 128) >> 11;
            const int tl0 = (bm * 128) & 2047;
            #pragma unroll
            for (int p = 0; p < 2; ++p) {
                if (wc == p) {
                    #pragma unroll
                    for (int mi = 0; mi < 4; ++mi) {
                        int ttw = wr * 64 + mi * 16 + kq * 4;
                        #pragma unroll
                        for (int ni = 0; ni < 4; ++ni) {
                            int vv = ni * 16 + r16;
                            unsigned lo = (unsigned)f2bf(acc[mi][ni][0]) | ((unsigned)f2bf(acc[mi][ni][1]) << 16);
                            unsigned hi = (unsigned)f2bf(acc[mi][ni][2]) | ((unsigned)f2bf(acc[mi][ni][3]) << 16);
                            uint2 pk; pk.x = lo; pk.y = hi;
                            *(uint2*)&SMEM[vv * 128 + (ttw ^ ((vv & 7) << 3))] = pk;
                        }
                    }
                }
                __syncthreads();
                #pragma unroll
                for (int it = 0; it < 4; ++it) {
                    int vv  = (tid >> 4) + it * 16;
                    int tt8 = (tid & 15) * 8;
                    uint4 q = *(const uint4*)&SMEM[vv * 128 + (tt8 ^ ((vv & 7) << 3))];
                    int vg = (bn - 8) * 128 + p * 64 + vv;
                    *(uint4*)(C2 + (size_t)vg * VTROW + bb * VTB + 16 + tl0 + tt8) = q;
                }
                __syncthreads();
            }
        }
    } else {   // MODE 2: fused h2 + out
        float o0[16], o1[16];
        #pragma unroll
        for (int t2 = 0; t2 < 16; ++t2) { o0[t2] = 0.0f; o1[t2] = 0.0f; }
        #pragma unroll
        for (int ni = 0; ni < 4; ++ni) {
            int col = bn * 128 + wc * 64 + ni * 16 + r16;
            float bv = bias[col];
            float2 wv = *(const float2*)(Wout + col * 2);
            #pragma unroll
            for (int mi = 0; mi < 4; ++mi)
                #pragma unroll
                for (int r = 0; r < 4; ++r) {
                    float v = fmaxf(acc[mi][ni][r] + bv, 0.0f);
                    o0[mi * 4 + r] += v * wv.x;
                    o1[mi * 4 + r] += v * wv.y;
                }
        }
        #pragma unroll
        for (int s = 1; s < 16; s <<= 1)
            #pragma unroll
            for (int t2 = 0; t2 < 16; ++t2) {
                o0[t2] += __shfl_xor(o0[t2], s);
                o1[t2] += __shfl_xor(o1[t2], s);
            }
        if (r16 == 0) {
            #pragma unroll
            for (int mi = 0; mi < 4; ++mi)
                #pragma unroll
                for (int r = 0; r < 4; ++r) {
                    int row = bm * 128 + wr * 64 + mi * 16 + kq * 4 + r;
                    atomicAdd(&outp[(size_t)row * 2],     o0[mi * 4 + r]);
                    atomicAdd(&outp[(size_t)row * 2 + 1], o1[mi * 4 + r]);
                }
        }
    }
}

// ---------------- banded attention via MFMA ----------------
__global__ __launch_bounds__(256) void attn_kernel(
    const unsigned short* __restrict__ Qb,   // [8192][512] bf16
    const unsigned short* __restrict__ Kb,   // [8192][512] bf16
    const unsigned short* __restrict__ Vt,   // [512][VTROW] bf16, zero pads
    float* __restrict__ attn_out,            // [8192][33]
    unsigned short* __restrict__ ctx)        // [8192][512] bf16
{
    __shared__ __align__(16) float Sl[4][32][66];          // stride 66: <=2-way banks
    __shared__ __align__(16) unsigned short Pl[32 * 64];   // XOR-swizzled [row][64]
    const int tid = threadIdx.x;
    const int lane = tid & 63;
    const int w = tid >> 6;                  // wave id = k-slice / d-slice
    const int t0g = blockIdx.x * 32;         // global row base
    const int b = t0g >> 11;
    const int t0 = t0g & 2047;               // local row base within batch
    const int r16 = lane & 15, kq = lane >> 4;

    // ---- Phase 1: partial S = Q * Kwin^T over k-slice [w*128, w*128+128)
    f32x4 s[2][4] = {};
    const unsigned short* qbase = Qb + (size_t)t0g * HID + w * 128 + kq * 8;
    const unsigned short* kbase = Kb + (long)(t0g - 16) * HID + w * 128 + kq * 8;
    #pragma unroll
    for (int ks = 0; ks < 4; ++ks) {
        short8 a0 = *(const short8*)(qbase + (size_t)r16 * HID + ks * 32);
        short8 a1 = *(const short8*)(qbase + (size_t)(16 + r16) * HID + ks * 32);
        #pragma unroll
        for (int ni = 0; ni < 4; ++ni) {
            short8 bf = *(const short8*)(kbase + (size_t)(ni * 16 + r16) * HID + ks * 32);
            s[0][ni] = __builtin_amdgcn_mfma_f32_16x16x32_bf16(a0, bf, s[0][ni], 0, 0, 0);
            s[1][ni] = __builtin_amdgcn_mfma_f32_16x16x32_bf16(a1, bf, s[1][ni], 0, 0, 0);
        }
    }
    #pragma unroll
    for (int mi = 0; mi < 2; ++mi)
        #pragma unroll
        for (int ni = 0; ni < 4; ++ni)
            #pragma unroll
            for (int r = 0; r < 4; ++r)
                Sl[w][mi * 16 + kq * 4 + r][ni * 16 + r16] = s[mi][ni][r];
    __syncthreads();

    // ---- Phase 2: reduce partials + masked softmax. Thread -> (row, 8 cols)
    {
        const int i = tid >> 3;            // row 0..31
        const int c8 = (tid & 7) * 8;      // col chunk base
        float sv[8];
        #pragma unroll
        for (int cc = 0; cc < 8; ++cc) {
            float a = Sl[0][i][c8 + cc] + Sl[1][i][c8 + cc]
                    + Sl[2][i][c8 + cc] + Sl[3][i][c8 + cc];
            int m = c8 + cc;
            bool inb = (m >= i) && (m <= i + 32);
            int krow = t0 + m - 16;
            bool inseq = (krow >= 0) && (krow < S_LEN);
            sv[cc] = inb ? (inseq ? a * SCALE_INV : 0.0f) : -INFINITY;
        }
        float mx = sv[0];
        #pragma unroll
        for (int cc = 1; cc < 8; ++cc) mx = fmaxf(mx, sv[cc]);
        mx = fmaxf(mx, __shfl_xor(mx, 1));
        mx = fmaxf(mx, __shfl_xor(mx, 2));
        mx = fmaxf(mx, __shfl_xor(mx, 4));
        float es = 0.0f;
        #pragma unroll
        for (int cc = 0; cc < 8; ++cc) { sv[cc] = __expf(sv[cc] - mx); es += sv[cc]; }
        es += __shfl_xor(es, 1);
        es += __shfl_xor(es, 2);
        es += __shfl_xor(es, 4);
        float inv = 1.0f / es;
        unsigned short pb[8];
        #pragma unroll
        for (int cc = 0; cc < 8; ++cc) {
            float p = sv[cc] * inv;
            pb[cc] = f2bf(p);
            int m = c8 + cc;
            if (m >= i && m <= i + 32)
                attn_out[(size_t)(t0g + i) * WIN + (i + 32 - m)] = p;
        }
        uint4 pk;
        pk.x = (unsigned)pb[0] | ((unsigned)pb[1] << 16);
        pk.y = (unsigned)pb[2] | ((unsigned)pb[3] << 16);
        pk.z = (unsigned)pb[4] | ((unsigned)pb[5] << 16);
        pk.w = (unsigned)pb[6] | ((unsigned)pb[7] << 16);
        *(uint4*)((char*)Pl + i * 128 + ((c8 * 2) ^ ((i & 7) << 4))) = pk;
    }
    __syncthreads();

    // ---- Phase 3: ctx slice [32 rows][d in w*128..+128) = P(32x64) * Vwin
    f32x4 c[2][8] = {};
    const char* plb = (const char*)Pl;
    const unsigned short* vtb = Vt + (size_t)b * VTB + t0;   // +16 pad and -16 window cancel
    #pragma unroll
    for (int ks = 0; ks < 2; ++ks) {
        int cb = ks * 64 + kq * 16;
        short8 a0 = *(const short8*)(plb + r16 * 128 + (cb ^ ((r16 & 7) << 4)));
        short8 a1 = *(const short8*)(plb + (16 + r16) * 128 + (cb ^ ((r16 & 7) << 4)));
        #pragma unroll
        for (int nd = 0; nd < 8; ++nd) {
            const unsigned short* vp = vtb + (size_t)(w * 128 + nd * 16 + r16) * VTROW + ks * 32 + kq * 8;
            short8 bf = *(const short8*)vp;
            c[0][nd] = __builtin_amdgcn_mfma_f32_16x16x32_bf16(a0, bf, c[0][nd], 0, 0, 0);
            c[1][nd] = __builtin_amdgcn_mfma_f32_16x16x32_bf16(a1, bf, c[1][nd], 0, 0, 0);
        }
    }
    #pragma unroll
    for (int mi = 0; mi < 2; ++mi) {
        int row0 = t0g + mi * 16 + kq * 4;
        #pragma unroll
        for (int nd = 0; nd < 8; ++nd) {
            int col = w * 128 + nd * 16 + r16;
            #pragma unroll
            for (int r = 0; r < 4; ++r)
                ctx[(size_t)(row0 + r) * HID + col] = f2bf(c[mi][nd][r]);
        }
    }
}

extern "C" void kernel_launch(void* const* d_in, const int* in_sizes, int n_in,
                              void* d_out, int out_size, void* d_ws, size_t ws_size,
                              hipStream_t stream)
{
    const float* x    = (const float*)d_in[0];
    const float* Wq   = (const float*)d_in[1];
    const float* Wk   = (const float*)d_in[2];
    const float* Wv   = (const float*)d_in[3];
    const float* W0   = (const float*)d_in[4];
    const float* b0   = (const float*)d_in[5];
    const float* W1   = (const float*)d_in[6];
    const float* b1   = (const float*)d_in[7];
    const float* Wout = (const float*)d_in[8];
    const float* bout = (const float*)d_in[9];

    char* ws = (char*)d_ws;
    unsigned short* xb    = (unsigned short*)(ws + 0);            // 4 MiB
    unsigned short* Wt0   = (unsigned short*)(ws + (4u  << 20));  // 256 KiB
    unsigned short* Wtqkv = (unsigned short*)(ws + 4456448u);     // 1.5 MiB [Wq^T;Wk^T;Wv^T]
    unsigned short* Wt1   = (unsigned short*)(ws + 6029312u);     // 512 KiB
    unsigned short* hB    = (unsigned short*)(ws + (8u  << 20));  // 8 MiB
    unsigned short* Qb    = (unsigned short*)(ws + (16u << 20));  // 8 MiB
    unsigned short* Kb    = (unsigned short*)(ws + (24u << 20));  // 8 MiB (safe +-16-row overread)
    unsigned short* Vt    = (unsigned short*)(ws + (32u << 20));  // 8.5 MiB [512][VTROW]
    unsigned short* ctxB  = (unsigned short*)(ws + (41u << 20));  // 8 MiB

    float* outp  = (float*)d_out;               // [8192][2]
    float* attnp = (float*)d_out + MROWS * 2;   // [8192][33]

    // 1) prep: convert x + W0 transpose only
    prep_kernel<<<2176, 256, 0, stream>>>(x, W0, xb, Wt0);

    // 2) h = relu(x @ W0 + b0); side blocks: Wq/Wk/Wv/W1 transposes, Vt pads, out init
    gemm128_kernel<DIN, 0><<<dim3(25, 64), 256, 0, stream>>>(
        xb, Wt0, b0, hB, nullptr, nullptr, nullptr, nullptr,
        Wq, Wk, Wv, W1, bout, Wtqkv, Wt1, Vt, outp);

    // 3) fused QKV GEMM (V written transposed into Vt via LDS bounce)
    gemm128_kernel<HID, 1><<<dim3(12, 64), 256, 0, stream>>>(
        hB, Wtqkv, nullptr, Qb, Kb, Vt, nullptr, nullptr,
        nullptr, nullptr, nullptr, nullptr, nullptr, nullptr, nullptr, nullptr, nullptr);

    // 4) banded attention
    attn_kernel<<<256, 256, 0, stream>>>(Qb, Kb, Vt, attnp, ctxB);

    // 5) h2 = relu(ctx @ W1 + b1); out = h2 @ Wout + bout (fused, atomic)
    gemm128_kernel<HID, 2><<<dim3(4, 64), 256, 0, stream>>>(
        ctxB, Wt1, b1, nullptr, nullptr, nullptr, Wout, outp,
        nullptr, nullptr, nullptr, nullptr, nullptr, nullptr, nullptr, nullptr, nullptr);
}

// Round 13
// 145.563 us; speedup vs baseline: 1.0531x; 1.0531x over previous
//
#include <hip/hip_runtime.h>

#define S_LEN 2048
#define HID 512
#define DIN 256
#define WIN 33
#define MROWS 8192
#define VTB 2080          // per-batch padded width of Vt (16 + 2048 + 16)
#define VTROW 8320        // 4 * VTB
#define SCALE_INV 0.04419417382415922f   // 1/sqrt(512)

typedef __attribute__((ext_vector_type(8))) short short8;
typedef __attribute__((ext_vector_type(4))) float f32x4;

__device__ __forceinline__ unsigned short f2bf(float f) {
    unsigned u = __builtin_bit_cast(unsigned, f);
    u += 0x7fffu + ((u >> 16) & 1u);
    return (unsigned short)(u >> 16);
}
__device__ __forceinline__ float bf2f(unsigned short h) {
    unsigned u = ((unsigned)h) << 16;
    return __builtin_bit_cast(float, u);
}
__device__ __forceinline__ void gl_lds16(const unsigned short* g, unsigned short* l) {
    __builtin_amdgcn_global_load_lds(
        (__attribute__((address_space(1))) unsigned int*)(g),
        (__attribute__((address_space(3))) unsigned int*)(l),
        16, 0, 0);
}

// ---------------- prep: x->bf16, out init, Vt pads, 5 weight transposes ----------------
__global__ __launch_bounds__(256) void prep_kernel(
    const float* __restrict__ x,
    const float* __restrict__ Wq, const float* __restrict__ Wk,
    const float* __restrict__ Wv, const float* __restrict__ W0,
    const float* __restrict__ W1, const float* __restrict__ bout,
    unsigned short* __restrict__ xb, unsigned short* __restrict__ Wt0,
    unsigned short* __restrict__ Wtqkv, unsigned short* __restrict__ Wt1,
    unsigned short* __restrict__ Vt, float* __restrict__ outp)
{
    __shared__ float tile[32][33];
    const int blk = blockIdx.x, tid = threadIdx.x;
    if (blk < 2048) {                        // convert x (2M elems, 4/thread)
        int i = (blk * 256 + tid) * 4;
        float4 v = *(const float4*)(x + i);
        unsigned lo = (unsigned)f2bf(v.x) | ((unsigned)f2bf(v.y) << 16);
        unsigned hi = (unsigned)f2bf(v.z) | ((unsigned)f2bf(v.w) << 16);
        uint2 p; p.x = lo; p.y = hi;
        *(uint2*)(xb + i) = p;
    } else if (blk < 2064) {                 // init out[8192][2] = bout
        int i = ((blk - 2048) * 256 + tid) * 4;
        float4 o; o.x = bout[0]; o.y = bout[1]; o.z = bout[0]; o.w = bout[1];
        *(float4*)(outp + i) = o;
    } else if (blk < 2320) {                 // zero Vt pads
        int t = (blk - 2064) * 256 + tid;    // 0..65535
        int v = t >> 7, s = t & 127;
        int b = s >> 5, p = s & 31;
        int off = (p < 16) ? p : (2048 + p);
        Vt[(size_t)v * VTROW + b * VTB + off] = 0;
    } else {                                 // weight transposes, 1152 tiles of 32x32
        int tt = blk - 2320;
        const float* in; unsigned short* out; int K, kt, nt;
        if (tt < 128) { in = W0; out = Wt0; K = DIN; kt = tt & 7; nt = tt >> 3; }
        else {
            int z = (tt - 128) >> 8, r = (tt - 128) & 255;
            kt = r & 15; nt = r >> 4; K = HID;
            if (z == 0)      { in = Wq; out = Wtqkv; }
            else if (z == 1) { in = Wk; out = Wtqkv + 512 * 512; }
            else if (z == 2) { in = Wv; out = Wtqkv + 2 * 512 * 512; }
            else             { in = W1; out = Wt1; }
        }
        int k0 = kt * 32, n0 = nt * 32;
        int tx = tid & 31, ty = tid >> 5;
        for (int j = 0; j < 32; j += 8)
            tile[ty + j][tx] = in[(size_t)(k0 + ty + j) * HID + n0 + tx];
        __syncthreads();
        for (int j = 0; j < 32; j += 8)
            out[(size_t)(n0 + ty + j) * K + k0 + tx] = f2bf(tile[tx][ty + j]);
    }
}

// ---------------- 128x128 MFMA GEMM, 3-buf pipeline, 2 tiles in flight (T3+T4) ----------------
// grid (NB_N, NB_M): blockIdx.x = bn (fastest), blockIdx.y = bm.
// MODE 0: C0 = relu(A@Bt^T + bias) bf16.
// MODE 1: QKV split (bn<4 -> C0=Q, bn<8 -> C1=K, else transposed LDS-bounced
//         write into C2=Vt).
// MODE 2: h2 = relu(A@Bt^T + bias); out += h2 @ Wout (atomicAdd, out pre-init
//         with bout). No h2 materialization.
template<int K, int MODE>
__global__ __launch_bounds__(256) void gemm128_kernel(
    const unsigned short* __restrict__ A,
    const unsigned short* __restrict__ Bt,
    const float* __restrict__ bias,
    unsigned short* __restrict__ C0,
    unsigned short* __restrict__ C1,
    unsigned short* __restrict__ C2,
    const float* __restrict__ Wout,
    float* __restrict__ outp)
{
    __shared__ __align__(16) unsigned short SMEM[24576];  // 3 bufs x (A 4096 | B 4096)
    const int tid = threadIdx.x;
    const int lane = tid & 63, wid = tid >> 6;
    const int bn = blockIdx.x, bm = blockIdx.y;
    const int wr = wid >> 1, wc = wid & 1;
    const int r16 = lane & 15, kq = lane >> 4;
    const int NT = K / 32;

    f32x4 acc[4][4] = {};

    const int c0 = tid, c1 = tid + 256;   // chunk = kblk*128 + row
    const unsigned short* aS0 = A + (size_t)(bm * 128 + (c0 & 127)) * K + (c0 >> 7) * 8;
    const unsigned short* aS1 = A + (size_t)(bm * 128 + (c1 & 127)) * K + (c1 >> 7) * 8;
    const unsigned short* bS0 = Bt + (size_t)(bn * 128 + (c0 & 127)) * K + (c0 >> 7) * 8;
    const unsigned short* bS1 = Bt + (size_t)(bn * 128 + (c1 & 127)) * K + (c1 >> 7) * 8;

    #define STAGE(buf, kt) do { \
        gl_lds16(aS0 + (kt) * 32, SMEM + (buf) * 8192 + c0 * 8); \
        gl_lds16(aS1 + (kt) * 32, SMEM + (buf) * 8192 + c1 * 8); \
        gl_lds16(bS0 + (kt) * 32, SMEM + (buf) * 8192 + 4096 + c0 * 8); \
        gl_lds16(bS1 + (kt) * 32, SMEM + (buf) * 8192 + 4096 + c1 * 8); \
    } while (0)

    STAGE(0, 0);
    STAGE(1, 1);
    int cur = 0;
    for (int kt = 0; kt < NT; ++kt) {
        if (kt + 2 < NT) {
            STAGE((cur + 2) % 3, kt + 2);
            // 12 outstanding -> drain to 8: tile kt landed, kt+1/kt+2 in flight
            asm volatile("s_waitcnt vmcnt(8)" ::: "memory");
        } else if (kt + 1 < NT) {
            asm volatile("s_waitcnt vmcnt(4)" ::: "memory");
        } else {
            asm volatile("s_waitcnt vmcnt(0)" ::: "memory");
        }
        __builtin_amdgcn_sched_barrier(0);
        __builtin_amdgcn_s_barrier();            // buf[cur] fully written, all waves
        __builtin_amdgcn_sched_barrier(0);

        const unsigned short* ab = SMEM + cur * 8192;
        const unsigned short* bb = ab + 4096;
        short8 af[4], bfr[4];
        #pragma unroll
        for (int mi = 0; mi < 4; ++mi)
            af[mi] = *(const short8*)(ab + kq * 1024 + (wr * 64 + mi * 16 + r16) * 8);
        #pragma unroll
        for (int ni = 0; ni < 4; ++ni)
            bfr[ni] = *(const short8*)(bb + kq * 1024 + (wc * 64 + ni * 16 + r16) * 8);
        #pragma unroll
        for (int mi = 0; mi < 4; ++mi)
            #pragma unroll
            for (int ni = 0; ni < 4; ++ni)
                acc[mi][ni] = __builtin_amdgcn_mfma_f32_16x16x32_bf16(af[mi], bfr[ni], acc[mi][ni], 0, 0, 0);

        asm volatile("s_waitcnt lgkmcnt(0)" ::: "memory");  // my ds_reads of buf[cur] done
        __builtin_amdgcn_sched_barrier(0);
        __builtin_amdgcn_s_barrier();            // everyone done reading buf[cur]
        __builtin_amdgcn_sched_barrier(0);
        cur = (cur + 1) % 3;
    }
    #undef STAGE

    if constexpr (MODE == 0) {
        #pragma unroll
        for (int mi = 0; mi < 4; ++mi) {
            int row0 = bm * 128 + wr * 64 + mi * 16 + kq * 4;
            #pragma unroll
            for (int ni = 0; ni < 4; ++ni) {
                int col = bn * 128 + wc * 64 + ni * 16 + r16;
                float bv = bias[col];
                #pragma unroll
                for (int r = 0; r < 4; ++r) {
                    float v = fmaxf(acc[mi][ni][r] + bv, 0.0f);
                    C0[(size_t)(row0 + r) * HID + col] = f2bf(v);
                }
            }
        }
    } else if constexpr (MODE == 1) {
        if (bn < 8) {
            unsigned short* dst = (bn < 4) ? C0 : C1;
            int cb = (bn & 3) * 128 + wc * 64;
            #pragma unroll
            for (int mi = 0; mi < 4; ++mi) {
                int row0 = bm * 128 + wr * 64 + mi * 16 + kq * 4;
                #pragma unroll
                for (int ni = 0; ni < 4; ++ni) {
                    int col = cb + ni * 16 + r16;
                    #pragma unroll
                    for (int r = 0; r < 4; ++r)
                        dst[(size_t)(row0 + r) * HID + col] = f2bf(acc[mi][ni][r]);
                }
            }
        } else {
            // V tile (rows t, cols v) -> Vt[v][t] via LDS bounce, 2 passes of 64 v-rows
            const int bb  = (bm * 128) >> 11;
            const int tl0 = (bm * 128) & 2047;
            #pragma unroll
            for (int p = 0; p < 2; ++p) {
                if (wc == p) {
                    #pragma unroll
                    for (int mi = 0; mi < 4; ++mi) {
                        int ttw = wr * 64 + mi * 16 + kq * 4;
                        #pragma unroll
                        for (int ni = 0; ni < 4; ++ni) {
                            int vv = ni * 16 + r16;
                            unsigned lo = (unsigned)f2bf(acc[mi][ni][0]) | ((unsigned)f2bf(acc[mi][ni][1]) << 16);
                            unsigned hi = (unsigned)f2bf(acc[mi][ni][2]) | ((unsigned)f2bf(acc[mi][ni][3]) << 16);
                            uint2 pk; pk.x = lo; pk.y = hi;
                            *(uint2*)&SMEM[vv * 128 + (ttw ^ ((vv & 7) << 3))] = pk;
                        }
                    }
                }
                __syncthreads();
                #pragma unroll
                for (int it = 0; it < 4; ++it) {
                    int vv  = (tid >> 4) + it * 16;
                    int tt8 = (tid & 15) * 8;
                    uint4 q = *(const uint4*)&SMEM[vv * 128 + (tt8 ^ ((vv & 7) << 3))];
                    int vg = (bn - 8) * 128 + p * 64 + vv;
                    *(uint4*)(C2 + (size_t)vg * VTROW + bb * VTB + 16 + tl0 + tt8) = q;
                }
                __syncthreads();
            }
        }
    } else {   // MODE 2: fused h2 + out
        float o0[16], o1[16];
        #pragma unroll
        for (int t2 = 0; t2 < 16; ++t2) { o0[t2] = 0.0f; o1[t2] = 0.0f; }
        #pragma unroll
        for (int ni = 0; ni < 4; ++ni) {
            int col = bn * 128 + wc * 64 + ni * 16 + r16;
            float bv = bias[col];
            float2 wv = *(const float2*)(Wout + col * 2);
            #pragma unroll
            for (int mi = 0; mi < 4; ++mi)
                #pragma unroll
                for (int r = 0; r < 4; ++r) {
                    float v = fmaxf(acc[mi][ni][r] + bv, 0.0f);
                    o0[mi * 4 + r] += v * wv.x;
                    o1[mi * 4 + r] += v * wv.y;
                }
        }
        #pragma unroll
        for (int s = 1; s < 16; s <<= 1)
            #pragma unroll
            for (int t2 = 0; t2 < 16; ++t2) {
                o0[t2] += __shfl_xor(o0[t2], s);
                o1[t2] += __shfl_xor(o1[t2], s);
            }
        if (r16 == 0) {
            #pragma unroll
            for (int mi = 0; mi < 4; ++mi)
                #pragma unroll
                for (int r = 0; r < 4; ++r) {
                    int row = bm * 128 + wr * 64 + mi * 16 + kq * 4 + r;
                    atomicAdd(&outp[(size_t)row * 2],     o0[mi * 4 + r]);
                    atomicAdd(&outp[(size_t)row * 2 + 1], o1[mi * 4 + r]);
                }
        }
    }
}

// ---------------- banded attention via MFMA ----------------
__global__ __launch_bounds__(256) void attn_kernel(
    const unsigned short* __restrict__ Qb,   // [8192][512] bf16
    const unsigned short* __restrict__ Kb,   // [8192][512] bf16
    const unsigned short* __restrict__ Vt,   // [512][VTROW] bf16, zero pads
    float* __restrict__ attn_out,            // [8192][33]
    unsigned short* __restrict__ ctx)        // [8192][512] bf16
{
    __shared__ __align__(16) float Sl[4][32][66];          // stride 66: <=2-way banks
    __shared__ __align__(16) unsigned short Pl[32 * 64];   // XOR-swizzled [row][64]
    const int tid = threadIdx.x;
    const int lane = tid & 63;
    const int w = tid >> 6;                  // wave id = k-slice / d-slice
    const int t0g = blockIdx.x * 32;         // global row base
    const int b = t0g >> 11;
    const int t0 = t0g & 2047;               // local row base within batch
    const int r16 = lane & 15, kq = lane >> 4;

    // ---- Phase 1: partial S = Q * Kwin^T over k-slice [w*128, w*128+128)
    f32x4 s[2][4] = {};
    const unsigned short* qbase = Qb + (size_t)t0g * HID + w * 128 + kq * 8;
    const unsigned short* kbase = Kb + (long)(t0g - 16) * HID + w * 128 + kq * 8;
    #pragma unroll
    for (int ks = 0; ks < 4; ++ks) {
        short8 a0 = *(const short8*)(qbase + (size_t)r16 * HID + ks * 32);
        short8 a1 = *(const short8*)(qbase + (size_t)(16 + r16) * HID + ks * 32);
        #pragma unroll
        for (int ni = 0; ni < 4; ++ni) {
            short8 bf = *(const short8*)(kbase + (size_t)(ni * 16 + r16) * HID + ks * 32);
            s[0][ni] = __builtin_amdgcn_mfma_f32_16x16x32_bf16(a0, bf, s[0][ni], 0, 0, 0);
            s[1][ni] = __builtin_amdgcn_mfma_f32_16x16x32_bf16(a1, bf, s[1][ni], 0, 0, 0);
        }
    }
    #pragma unroll
    for (int mi = 0; mi < 2; ++mi)
        #pragma unroll
        for (int ni = 0; ni < 4; ++ni)
            #pragma unroll
            for (int r = 0; r < 4; ++r)
                Sl[w][mi * 16 + kq * 4 + r][ni * 16 + r16] = s[mi][ni][r];
    __syncthreads();

    // ---- Phase 2: reduce partials + masked softmax. Thread -> (row, 8 cols)
    {
        const int i = tid >> 3;            // row 0..31
        const int c8 = (tid & 7) * 8;      // col chunk base
        float sv[8];
        #pragma unroll
        for (int cc = 0; cc < 8; ++cc) {
            float a = Sl[0][i][c8 + cc] + Sl[1][i][c8 + cc]
                    + Sl[2][i][c8 + cc] + Sl[3][i][c8 + cc];
            int m = c8 + cc;
            bool inb = (m >= i) && (m <= i + 32);
            int krow = t0 + m - 16;
            bool inseq = (krow >= 0) && (krow < S_LEN);
            sv[cc] = inb ? (inseq ? a * SCALE_INV : 0.0f) : -INFINITY;
        }
        float mx = sv[0];
        #pragma unroll
        for (int cc = 1; cc < 8; ++cc) mx = fmaxf(mx, sv[cc]);
        mx = fmaxf(mx, __shfl_xor(mx, 1));
        mx = fmaxf(mx, __shfl_xor(mx, 2));
        mx = fmaxf(mx, __shfl_xor(mx, 4));
        float es = 0.0f;
        #pragma unroll
        for (int cc = 0; cc < 8; ++cc) { sv[cc] = __expf(sv[cc] - mx); es += sv[cc]; }
        es += __shfl_xor(es, 1);
        es += __shfl_xor(es, 2);
        es += __shfl_xor(es, 4);
        float inv = 1.0f / es;
        unsigned short pb[8];
        #pragma unroll
        for (int cc = 0; cc < 8; ++cc) {
            float p = sv[cc] * inv;
            pb[cc] = f2bf(p);
            int m = c8 + cc;
            if (m >= i && m <= i + 32)
                attn_out[(size_t)(t0g + i) * WIN + (i + 32 - m)] = p;
        }
        uint4 pk;
        pk.x = (unsigned)pb[0] | ((unsigned)pb[1] << 16);
        pk.y = (unsigned)pb[2] | ((unsigned)pb[3] << 16);
        pk.z = (unsigned)pb[4] | ((unsigned)pb[5] << 16);
        pk.w = (unsigned)pb[6] | ((unsigned)pb[7] << 16);
        *(uint4*)((char*)Pl + i * 128 + ((c8 * 2) ^ ((i & 7) << 4))) = pk;
    }
    __syncthreads();

    // ---- Phase 3: ctx slice [32 rows][d in w*128..+128) = P(32x64) * Vwin
    f32x4 c[2][8] = {};
    const char* plb = (const char*)Pl;
    const unsigned short* vtb = Vt + (size_t)b * VTB + t0;   // +16 pad and -16 window cancel
    #pragma unroll
    for (int ks = 0; ks < 2; ++ks) {
        int cb = ks * 64 + kq * 16;
        short8 a0 = *(const short8*)(plb + r16 * 128 + (cb ^ ((r16 & 7) << 4)));
        short8 a1 = *(const short8*)(plb + (16 + r16) * 128 + (cb ^ ((r16 & 7) << 4)));
        #pragma unroll
        for (int nd = 0; nd < 8; ++nd) {
            const unsigned short* vp = vtb + (size_t)(w * 128 + nd * 16 + r16) * VTROW + ks * 32 + kq * 8;
            short8 bf = *(const short8*)vp;
            c[0][nd] = __builtin_amdgcn_mfma_f32_16x16x32_bf16(a0, bf, c[0][nd], 0, 0, 0);
            c[1][nd] = __builtin_amdgcn_mfma_f32_16x16x32_bf16(a1, bf, c[1][nd], 0, 0, 0);
        }
    }
    #pragma unroll
    for (int mi = 0; mi < 2; ++mi) {
        int row0 = t0g + mi * 16 + kq * 4;
        #pragma unroll
        for (int nd = 0; nd < 8; ++nd) {
            int col = w * 128 + nd * 16 + r16;
            #pragma unroll
            for (int r = 0; r < 4; ++r)
                ctx[(size_t)(row0 + r) * HID + col] = f2bf(c[mi][nd][r]);
        }
    }
}

extern "C" void kernel_launch(void* const* d_in, const int* in_sizes, int n_in,
                              void* d_out, int out_size, void* d_ws, size_t ws_size,
                              hipStream_t stream)
{
    const float* x    = (const float*)d_in[0];
    const float* Wq   = (const float*)d_in[1];
    const float* Wk   = (const float*)d_in[2];
    const float* Wv   = (const float*)d_in[3];
    const float* W0   = (const float*)d_in[4];
    const float* b0   = (const float*)d_in[5];
    const float* W1   = (const float*)d_in[6];
    const float* b1   = (const float*)d_in[7];
    const float* Wout = (const float*)d_in[8];
    const float* bout = (const float*)d_in[9];

    char* ws = (char*)d_ws;
    unsigned short* xb    = (unsigned short*)(ws + 0);            // 4 MiB
    unsigned short* Wt0   = (unsigned short*)(ws + (4u  << 20));  // 256 KiB
    unsigned short* Wtqkv = (unsigned short*)(ws + 4456448u);     // 1.5 MiB [Wq^T;Wk^T;Wv^T]
    unsigned short* Wt1   = (unsigned short*)(ws + 6029312u);     // 512 KiB
    unsigned short* hB    = (unsigned short*)(ws + (8u  << 20));  // 8 MiB
    unsigned short* Qb    = (unsigned short*)(ws + (16u << 20));  // 8 MiB
    unsigned short* Kb    = (unsigned short*)(ws + (24u << 20));  // 8 MiB (safe +-16-row overread)
    unsigned short* Vt    = (unsigned short*)(ws + (32u << 20));  // 8.5 MiB [512][VTROW]
    unsigned short* ctxB  = (unsigned short*)(ws + (41u << 20));  // 8 MiB

    float* outp  = (float*)d_out;               // [8192][2]
    float* attnp = (float*)d_out + MROWS * 2;   // [8192][33]

    // 1) prep: convert x, init out with bout, Vt pads, 5 weight transposes
    prep_kernel<<<3472, 256, 0, stream>>>(x, Wq, Wk, Wv, W0, W1, bout,
                                          xb, Wt0, Wtqkv, Wt1, Vt, outp);

    // 2) h = relu(x @ W0 + b0)        grid (bn fastest, bm)
    gemm128_kernel<DIN, 0><<<dim3(4, 64), 256, 0, stream>>>(
        xb, Wt0, b0, hB, nullptr, nullptr, nullptr, nullptr);

    // 3) fused QKV GEMM (V written transposed into Vt via LDS bounce)
    gemm128_kernel<HID, 1><<<dim3(12, 64), 256, 0, stream>>>(
        hB, Wtqkv, nullptr, Qb, Kb, Vt, nullptr, nullptr);

    // 4) banded attention
    attn_kernel<<<256, 256, 0, stream>>>(Qb, Kb, Vt, attnp, ctxB);

    // 5) h2 = relu(ctx @ W1 + b1); out = h2 @ Wout + bout (fused, atomic)
    gemm128_kernel<HID, 2><<<dim3(4, 64), 256, 0, stream>>>(
        ctxB, Wt1, b1, nullptr, nullptr, nullptr, Wout, outp);
}